// Round 8
// baseline (640.175 us; speedup 1.0000x reference)
//
#include <hip/hip_runtime.h>
#include <hip/hip_bf16.h>
#include <cstdint>
#include <cstddef>
#include <cmath>

#define TID ((int)threadIdx.x)

typedef __attribute__((ext_vector_type(8))) short bf16x8;
typedef __attribute__((ext_vector_type(4))) float f32x4;
typedef __attribute__((ext_vector_type(4))) unsigned short us4;
typedef unsigned short ushort_t;

__device__ __forceinline__ float bfu2f(unsigned short u){
    unsigned int x = ((unsigned int)u) << 16; float f; __builtin_memcpy(&f, &x, 4); return f;
}
__device__ __forceinline__ unsigned short f2bu(float f){
    __hip_bfloat16 b = __float2bfloat16(f); unsigned short u; __builtin_memcpy(&u, &b, 2); return u;
}
__device__ __forceinline__ float sigm(float x){
    return __builtin_amdgcn_rcpf(1.0f + __expf(-x));
}
__device__ __forceinline__ float tanhx(float x){
    return 1.0f - 2.0f*__builtin_amdgcn_rcpf(1.0f + __expf(2.0f*x));
}

// ============ K1: prep: Whh/Wih A-frag swizzles, gate-interleaved bias, GAT W@a vectors ============
__global__ __launch_bounds__(256) void k_prep(
    const float* __restrict__ Wih_f, const float* __restrict__ Wih_b, const float* __restrict__ Wih_p,
    const float* __restrict__ Whh_f, const float* __restrict__ Whh_b, const float* __restrict__ Whh_p,
    const float* __restrict__ b_f, const float* __restrict__ b_b, const float* __restrict__ b_p,
    const float* __restrict__ W1, const float* __restrict__ a1,
    const float* __restrict__ W2, const float* __restrict__ a2,
    unsigned short* __restrict__ Asw3, unsigned short* __restrict__ Wsw3,
    float* __restrict__ bI3,
    float* __restrict__ w1a, float* __restrict__ w1b,
    float* __restrict__ w2a, float* __restrict__ w2b)
{
    int bx = blockIdx.x;
    if (bx < 1200){
        int isW = (bx >= 600) ? 1 : 0;
        int e = (bx - isW*600)*256 + TID;     // 600*256 = 153600 exactly
        int l = e/51200, r = e - l*51200;
        int frag = r >> 9, q = r & 511;
        int lanep = q >> 3, j = q & 7;
        int mt = frag >> 2, kt = frag & 3;
        int m = mt*16 + (lanep & 15);
        int f = m >> 2, gg = m & 3;
        int k = kt*32 + (lanep >> 4)*8 + j;
        const float* Ws = isW ? ((l==0)?Wih_f:(l==1)?Wih_b:Wih_p)
                              : ((l==0)?Whh_f:(l==1)?Whh_b:Whh_p);
        float v = (k < 100) ? Ws[(gg*100+f)*100 + k] : 0.f;
        (isW ? Wsw3 : Asw3)[e] = f2bu(v);
    } else if (bx == 1200){
        for (int e=TID; e<1200; e+=256){
            int l = e/400, m = e - l*400;
            int f = m >> 2, gg = m & 3;
            const float* bb = (l==0)?b_f:(l==1)?b_b:b_p;
            bI3[e] = bb[gg*100+f];
        }
    } else {
        int lane = TID & 63, w = TID >> 6;
        int r = (bx - 1201)*4 + w;            // 0..699
        if (r < 600){
            float x=0.f, y=0.f;
            for (int k=lane;k<600;k+=64){ float wv=W1[r*600+k]; x+=wv*a1[k]; y+=wv*a1[600+k]; }
#pragma unroll
            for (int off=32;off>0;off>>=1){ x+=__shfl_down(x,off,64); y+=__shfl_down(y,off,64); }
            if (lane==0){ w1a[r]=x; w1b[r]=y; }
        } else if (r < 700){
            int f = r-600;
            float x=0.f, y=0.f;
            for (int k=lane;k<100;k+=64){ float wv=W2[f*100+k]; x+=wv*a2[k]; y+=wv*a2[100+k]; }
#pragma unroll
            for (int off=32;off>0;off>>=1){ x+=__shfl_down(x,off,64); y+=__shfl_down(y,off,64); }
            if (lane==0){ w2a[f]=x; w2b[f]=y; }
        }
    }
}

// ============ K2: MFMA input projection: P'[row][f*4+g] = emb@Wih^T + b (bf16) ============
__global__ __launch_bounds__(256) void k_projm(
    const float* __restrict__ ent, const float* __restrict__ rel,
    const float* __restrict__ ent1, const float* __restrict__ rel1,
    const unsigned short* __restrict__ Wsw3, const float* __restrict__ bI3,
    unsigned short* __restrict__ Pfe, unsigned short* __restrict__ Pfr,
    unsigned short* __restrict__ Pbe, unsigned short* __restrict__ Pbr,
    unsigned short* __restrict__ Ppe, unsigned short* __restrict__ Ppr)
{
    int y = blockIdx.y;
    int l = y >> 1;
    int isrel = y & 1;
    int rows = isrel ? 237 : 14541;
    int r0 = blockIdx.x * 64;
    if (r0 >= rows) return;
    const float* emb  = isrel ? ((l==2)? rel1 : rel) : ((l==2)? ent1 : ent);
    unsigned short* P = (y==0)?Pfe:(y==1)?Pfr:(y==2)?Pbe:(y==3)?Pbr:(y==4)?Ppe:Ppr;
    const unsigned short* A = Wsw3 + l*51200;
    const float* bI = bI3 + l*400;

    __shared__ __align__(16) ushort_t EB[64][136];
    for (int idx=TID; idx<64*128; idx+=256){
        int r = idx >> 7, k = idx & 127;
        int rg = r0 + r;
        float v = (rg < rows && k < 100) ? emb[rg*100 + k] : 0.f;
        EB[r][k] = f2bu(v);
    }
    __syncthreads();

    int lane = TID & 63, w = TID >> 6, l15 = lane & 15, quad = lane >> 4;
    int rg = r0 + w*16 + l15;
    bf16x8 bfr[4];
#pragma unroll
    for (int kt=0;kt<4;kt++) bfr[kt] = *(const bf16x8*)&EB[w*16 + l15][kt*32 + quad*8];

    for (int mt=0; mt<25; mt++){
        f32x4 acc = (f32x4){0.f,0.f,0.f,0.f};
#pragma unroll
        for (int kt=0;kt<4;kt++){
            bf16x8 af = *(const bf16x8*)(A + ((mt*4+kt)*64 + lane)*8);
            acc = __builtin_amdgcn_mfma_f32_16x16x32_bf16(af, bfr[kt], acc, 0, 0, 0);
        }
        f32x4 bv = *(const f32x4*)(bI + mt*16 + quad*4);
        us4 o;
#pragma unroll
        for (int r=0;r<4;r++) o[r] = f2bu(acc[r] + bv[r]);
        if (rg < rows) *(us4*)(P + (size_t)rg*400 + mt*16 + quad*4) = o;
    }
}

// ============ K3: 3xLSTM, MFMA recurrence, LDS-staged P (coalesced), h -> global out ============
// One block per 40-sample group. All barriers are full __syncthreads (race-class eliminated).
__global__ __launch_bounds__(256, 3) void k_lstm(
    const int* __restrict__ bh, const int* __restrict__ br, const int* __restrict__ bt,
    const unsigned short* __restrict__ Pfe, const unsigned short* __restrict__ Pfr,
    const unsigned short* __restrict__ Pbe, const unsigned short* __restrict__ Pbr,
    const unsigned short* __restrict__ Ppe, const unsigned short* __restrict__ Ppr,
    const unsigned short* __restrict__ Asw3,
    const float* __restrict__ w2a, const float* __restrict__ w2b,
    unsigned short* __restrict__ out, float* __restrict__ z2,
    float* __restrict__ out0, float* __restrict__ op0)
{
    __shared__ __align__(16) ushort_t Pst[40][408];   // staged gate rows (32.6 KB)
    __shared__ __align__(16) ushort_t HA[48][136];    // current h (B operand) 13.1 KB
    __shared__ float S0o[600];
    __shared__ float S0p[100];
    __shared__ float sc2[40], tc2[40], att2[40];
    __shared__ int sidx[3][40];

    int g = blockIdx.x, m0 = g*40;
    if (TID < 40){
        sidx[0][TID] = bh[m0+TID];
        sidx[1][TID] = br[m0+TID];
        sidx[2][TID] = bt[m0+TID];
    }
    {   // zero HA fully: 48*136 shorts = 6528 shorts = 1632 us4 (8B each)
        us4 zz; zz[0]=0; zz[1]=0; zz[2]=0; zz[3]=0;
        for (int i=TID; i<1632; i+=256) ((us4*)HA)[i] = zz;
    }
    __syncthreads();

    int lane = TID & 63;
    int wid  = TID >> 6;
    int l15  = lane & 15;
    int quad = lane >> 4;
    int nmt  = (wid==0) ? 7 : 6;          // m-tiles: wid + 4*i < 25
    bool doS0 = ((g & 1) == 0);
    int rrow = g >> 1;

    const unsigned short* PeA[3] = {Pfe, Pbe, Ppe};
    const unsigned short* PrA[3] = {Pfr, Pbr, Ppr};

    float c[21];
    int prevbase = -1;                    // outH slot of h currently in HA (pending store)

    for (int l=0; l<3; l++){
        const unsigned short* Aswl = Asw3 + l*51200;
        for (int t=0; t<3; t++){
            int p = (l==1) ? (2-t) : t;
            const unsigned short* tab = (p==1) ? PrA[l] : PeA[l];

            // ---- phase 1: store prev h -> out (coalesced); stage P rows; read bfr
            if (prevbase >= 0){
                for (int idx=TID; idx<1000; idx+=256){   // 40 rows x 25 chunks of 8B
                    int s = idx/25, ch = idx - s*25;
                    *(us4*)(out + (size_t)(m0+s)*600 + prevbase + ch*4) =
                        *(const us4*)&HA[s][ch*4];
                }
            }
            for (int idx=TID; idx<2000; idx+=256){       // 40 rows x 50 chunks of 16B
                int s = idx/50, ch = idx - s*50;
                *(bf16x8*)&Pst[s][ch*8] =
                    *(const bf16x8*)(tab + (size_t)sidx[p][s]*400 + ch*8);
            }
            bf16x8 bfr[3][4];
            if (t > 0){
#pragma unroll
                for (int nt=0;nt<3;nt++)
#pragma unroll
                    for (int kt=0;kt<4;kt++)
                        bfr[nt][kt] = *(const bf16x8*)&HA[nt*16 + l15][kt*32 + quad*8];
            }
            __syncthreads();

            // ---- phase 2: MFMA + cell updates (P from LDS)
            int wbase = (l==0) ? t*200 : (l==1) ? (2-t)*200 + 100 : 0;
#pragma unroll
            for (int i=0;i<7;i++){
                if (i < nmt){
                    f32x4 acc3[3];
#pragma unroll
                    for (int nt=0;nt<3;nt++) acc3[nt] = (f32x4){0.f,0.f,0.f,0.f};
                    if (t > 0){
                        int mt = wid + 4*i;
#pragma unroll
                        for (int kt=0;kt<4;kt++){
                            bf16x8 af = *(const bf16x8*)(Aswl + ((mt*4+kt)*64 + lane)*8);
#pragma unroll
                            for (int nt=0;nt<3;nt++)
                                acc3[nt] = __builtin_amdgcn_mfma_f32_16x16x32_bf16(
                                    af, bfr[nt][kt], acc3[nt], 0, 0, 0);
                        }
                    }
                    int f = (wid + 4*i)*4 + quad;    // 0..99
#pragma unroll
                    for (int nt=0;nt<3;nt++){
                        int s = nt*16 + l15;
                        bool valid = (nt < 2) || (l15 < 8);
                        int sr = valid ? s : 0;
                        us4 p4 = *(const us4*)&Pst[sr][f*4];
                        f32x4 a4 = acc3[nt];
                        float gi = a4[0] + bfu2f(p4[0]);
                        float gf = a4[1] + bfu2f(p4[1]);
                        float gg = a4[2] + bfu2f(p4[2]);
                        float go = a4[3] + bfu2f(p4[3]);
                        float cp = (t==0) ? 0.f : c[i*3+nt];
                        float cn = sigm(gf)*cp + sigm(gi)*tanhx(gg);
                        float h  = sigm(go)*tanhx(cn);
                        c[i*3+nt] = cn;
                        if (valid){
                            HA[s][f] = f2bu(h);
                            if (doS0 && s==0){
                                if (l < 2)            S0o[wbase + f] = h;
                                else if (t == 2)      S0p[f] = h;
                            }
                        }
                    }
                }
            }
            prevbase = (l==2) ? -1 : wbase;
            __syncthreads();
        }
    }
    // HA cols 0..99 hold final proc-LSTM h.

    // ---- proc-branch attention (set 2)
    for (int n = wid; n < 40; n += 4){
        float a2=0.f, b2=0.f;
        for (int k=lane;k<100;k+=64){ float v=bfu2f(HA[n][k]); a2 += v*w2a[k]; b2 += v*w2b[k]; }
#pragma unroll
        for (int off=32; off>0; off>>=1){ a2 += __shfl_down(a2,off,64); b2 += __shfl_down(b2,off,64); }
        if (lane==0){ sc2[n]=a2; tc2[n]=b2; }
    }
    __syncthreads();
    if (wid == 0){
        float e = -1e30f;
        if (lane < 40){
            float x = sc2[lane] + tc2[0];
            e = (x > 0.f) ? x : 0.2f*x;
        }
        float mx = e;
#pragma unroll
        for (int off=32;off>0;off>>=1) mx = fmaxf(mx, __shfl_down(mx,off,64));
        mx = __shfl(mx, 0, 64);
        float pexp = (lane<40) ? __expf(e-mx) : 0.f;
        float sm = pexp;
#pragma unroll
        for (int off=32;off>0;off>>=1) sm += __shfl_down(sm,off,64);
        sm = __shfl(sm, 0, 64);
        if (lane < 40){
            float a = pexp/sm - 0.001f;
            att2[lane] = (a > 0.f) ? a : 0.f;
        }
    }
    __syncthreads();
    for (int j=TID; j<100; j+=256){
        float acc = 0.f;
#pragma unroll
        for (int n=0;n<40;n++) acc += att2[n]*bfu2f(HA[n][j]);
        z2[(size_t)g*100 + j] = acc;
    }
    if (doS0){
        for (int j=TID; j<600; j+=256) out0[(size_t)rrow*600 + j] = S0o[j];
        for (int j=TID; j<100; j+=256) op0[(size_t)rrow*100 + j] = S0p[j];
    }
}

// ============ K4: BiLSTM-branch attention: dots + softmax + z, per 40-sample group ============
__global__ __launch_bounds__(256, 3) void k_att(const unsigned short* __restrict__ out,
    const float* __restrict__ w1a, const float* __restrict__ w1b, float* __restrict__ z)
{
    __shared__ __align__(16) ushort_t RL[40][600];
    __shared__ float sc1[40], tc1[40], att1[40];
    int g = blockIdx.x, m0 = g*40;
    for (int idx=TID; idx<3000; idx+=256){   // 40 rows x 75 chunks of 16B
        int n = idx/75, ch = idx - n*75;
        *(bf16x8*)&RL[n][ch*8] = *(const bf16x8*)(out + (size_t)(m0+n)*600 + ch*8);
    }
    __syncthreads();
    int lane = TID & 63, wid = TID >> 6;
    for (int n = wid; n < 40; n += 4){
        float a=0.f, b=0.f;
        for (int k=lane;k<600;k+=64){ float v=bfu2f(RL[n][k]); a += v*w1a[k]; b += v*w1b[k]; }
#pragma unroll
        for (int off=32; off>0; off>>=1){ a += __shfl_down(a,off,64); b += __shfl_down(b,off,64); }
        if (lane==0){ sc1[n]=a; tc1[n]=b; }
    }
    __syncthreads();
    if (wid == 0){
        float e = -1e30f;
        if (lane < 40){
            float x = sc1[lane] + tc1[0];
            e = (x > 0.f) ? x : 0.2f*x;
        }
        float mx = e;
#pragma unroll
        for (int off=32;off>0;off>>=1) mx = fmaxf(mx, __shfl_down(mx,off,64));
        mx = __shfl(mx, 0, 64);
        float pexp = (lane<40) ? __expf(e-mx) : 0.f;
        float sm = pexp;
#pragma unroll
        for (int off=32;off>0;off>>=1) sm += __shfl_down(sm,off,64);
        sm = __shfl(sm, 0, 64);
        if (lane < 40){
            float a = pexp/sm - 0.001f;
            att1[lane] = (a > 0.f) ? a : 0.f;
        }
    }
    __syncthreads();
    for (int j=TID; j<600; j+=256){
        float acc = 0.f;
#pragma unroll
        for (int n=0;n<40;n++) acc += att1[n]*bfu2f(RL[n][j]);
        z[(size_t)g*600 + j] = acc;
    }
}

// ============ K5: merged final GEMMs: y<3 -> oatt (600 col-chunks), y==3 -> oatt2 (100) ====
__global__ __launch_bounds__(256) void k_post(const float* __restrict__ z, const float* __restrict__ z2,
    const float* __restrict__ W1, const float* __restrict__ W2,
    float* __restrict__ oatt, float* __restrict__ oatt2)
{
    extern __shared__ float zl[];
    int y = blockIdx.y;
    const float* zz = (y==3)? z2 : z;
    const float* W  = (y==3)? W2 : W1;
    float* o        = (y==3)? oatt2 : oatt;
    int dim         = (y==3)? 100 : 600;
    int rb = blockIdx.x*16;
    for (int r=0;r<16;r++){
        for (int j=TID;j<dim;j+=256) zl[r*dim+j] = zz[(size_t)(rb+r)*dim + j];
    }
    __syncthreads();
    int cc = (y==3)? TID : y*256 + TID;
    if (cc < dim){
        float acc[16];
#pragma unroll
        for (int r=0;r<16;r++) acc[r]=0.f;
        for (int k=0;k<dim;k++){
            float w = W[(size_t)k*dim + cc];
#pragma unroll
            for (int r=0;r<16;r++) acc[r] += zl[r*dim+k]*w;
        }
        for (int r=0;r<16;r++) o[(size_t)(rb+r)*dim + cc] = acc[r];
    }
}

__global__ void k_sentinel(float* o, float v){ o[0] = v; }

extern "C" void kernel_launch(void* const* d_in, const int* in_sizes, int n_in,
                              void* d_out, int out_size, void* d_ws, size_t ws_size,
                              hipStream_t stream)
{
    const int*   bh   = (const int*)d_in[0];
    const int*   br   = (const int*)d_in[1];
    const int*   bt   = (const int*)d_in[2];
    const float* ent  = (const float*)d_in[3];
    const float* rel  = (const float*)d_in[4];
    const float* ent1 = (const float*)d_in[5];
    const float* rel1 = (const float*)d_in[6];
    const float* Wih_f = (const float*)d_in[7];
    const float* Whh_f = (const float*)d_in[8];
    const float* b_f   = (const float*)d_in[9];
    const float* Wih_b = (const float*)d_in[10];
    const float* Whh_b = (const float*)d_in[11];
    const float* b_b   = (const float*)d_in[12];
    const float* Wih_p = (const float*)d_in[13];
    const float* Whh_p = (const float*)d_in[14];
    const float* b_p   = (const float*)d_in[15];
    const float* W1 = (const float*)d_in[16];
    const float* a1 = (const float*)d_in[17];
    const float* W2 = (const float*)d_in[18];
    const float* a2 = (const float*)d_in[19];

    char* wsb = (char*)d_ws;
    size_t off = 0;
    auto alloc = [&](size_t bytes) -> char* {
        char* p = wsb + off;
        off += (bytes + 255) & ~(size_t)255;
        return p;
    };
    unsigned short* Pfe = (unsigned short*)alloc((size_t)14541*400*2);
    unsigned short* Pbe = (unsigned short*)alloc((size_t)14541*400*2);
    unsigned short* Ppe = (unsigned short*)alloc((size_t)14541*400*2);
    unsigned short* Pfr = (unsigned short*)alloc((size_t)237*400*2);
    unsigned short* Pbr = (unsigned short*)alloc((size_t)237*400*2);
    unsigned short* Ppr = (unsigned short*)alloc((size_t)237*400*2);
    unsigned short* Asw3 = (unsigned short*)alloc((size_t)153600*2);
    unsigned short* Wsw3 = (unsigned short*)alloc((size_t)153600*2);
    float* bI3 = (float*)alloc(1200*4);
    float* w1a = (float*)alloc(600*4);
    float* w1b = (float*)alloc(600*4);
    float* w2a = (float*)alloc(100*4);
    float* w2b = (float*)alloc(100*4);
    float* z   = (float*)alloc((size_t)2048*600*4);
    float* z2  = (float*)alloc((size_t)2048*100*4);
    unsigned short* outH = (unsigned short*)alloc((size_t)81920*600*2);   // 98.3 MB

    float* dout  = (float*)d_out;
    float* out0  = dout;              // out2[:,0,:]  1024*600
    float* oatt  = dout + 614400;     // out_att      2048*600
    float* op0   = dout + 1843200;    // op2[:,0,:]   1024*100
    float* oatt2 = dout + 1945600;    // output_att   2048*100

    if (ws_size < off){
        k_sentinel<<<1,1,0,stream>>>(dout, (float)ws_size);
        return;
    }

    k_prep<<<1376, 256, 0, stream>>>(Wih_f, Wih_b, Wih_p, Whh_f, Whh_b, Whh_p,
                                     b_f, b_b, b_p, W1, a1, W2, a2,
                                     Asw3, Wsw3, bI3, w1a, w1b, w2a, w2b);

    k_projm<<<dim3(228,6), 256, 0, stream>>>(ent, rel, ent1, rel1, Wsw3, bI3,
                                             Pfe, Pfr, Pbe, Pbr, Ppe, Ppr);

    k_lstm<<<2048, 256, 0, stream>>>(bh, br, bt, Pfe, Pfr, Pbe, Pbr, Ppe, Ppr,
                                     Asw3, w2a, w2b, outH, z2, out0, op0);

    k_att<<<2048, 256, 0, stream>>>(outH, w1a, w1b, z);

    k_post<<<dim3(128,4), 256, 16*600*4, stream>>>(z, z2, W1, W2, oatt, oatt2);
}

// Round 9
// 513.087 us; speedup vs baseline: 1.2477x; 1.2477x over previous
//
#include <hip/hip_runtime.h>
#include <hip/hip_bf16.h>
#include <cstdint>
#include <cstddef>
#include <cmath>

#define TID ((int)threadIdx.x)

typedef __attribute__((ext_vector_type(8))) short bf16x8;
typedef __attribute__((ext_vector_type(4))) float f32x4;
typedef __attribute__((ext_vector_type(4))) unsigned short us4;
typedef unsigned short ushort_t;

__device__ __forceinline__ float bfu2f(unsigned short u){
    unsigned int x = ((unsigned int)u) << 16; float f; __builtin_memcpy(&f, &x, 4); return f;
}
__device__ __forceinline__ unsigned short f2bu(float f){
    __hip_bfloat16 b = __float2bfloat16(f); unsigned short u; __builtin_memcpy(&u, &b, 2); return u;
}
__device__ __forceinline__ float sigm(float x){
    return __builtin_amdgcn_rcpf(1.0f + __expf(-x));
}
__device__ __forceinline__ float tanhx(float x){
    return 1.0f - 2.0f*__builtin_amdgcn_rcpf(1.0f + __expf(2.0f*x));
}

// ============ K1: prep ============
// Asw3: Whh A-frag swizzle (k=100.. zero). Wsw3: Wih A-frag swizzle with BIAS folded at k==100.
// Plus GAT W@a vectors and bf16 embedding tables.
__global__ __launch_bounds__(256) void k_prep(
    const float* __restrict__ Wih_f, const float* __restrict__ Wih_b, const float* __restrict__ Wih_p,
    const float* __restrict__ Whh_f, const float* __restrict__ Whh_b, const float* __restrict__ Whh_p,
    const float* __restrict__ b_f, const float* __restrict__ b_b, const float* __restrict__ b_p,
    const float* __restrict__ W1, const float* __restrict__ a1,
    const float* __restrict__ W2, const float* __restrict__ a2,
    const float* __restrict__ ent, const float* __restrict__ rel,
    const float* __restrict__ ent1, const float* __restrict__ rel1,
    unsigned short* __restrict__ Asw3, unsigned short* __restrict__ Wsw3,
    float* __restrict__ w1a, float* __restrict__ w1b,
    float* __restrict__ w2a, float* __restrict__ w2b,
    unsigned short* __restrict__ entB, unsigned short* __restrict__ relB,
    unsigned short* __restrict__ ent1B, unsigned short* __restrict__ rel1B)
{
    int bx = blockIdx.x;
    if (bx < 1200){
        int isW = (bx >= 600) ? 1 : 0;
        int e = (bx - isW*600)*256 + TID;     // 600*256 = 153600 exactly
        int l = e/51200, r = e - l*51200;
        int frag = r >> 9, q = r & 511;
        int lanep = q >> 3, j = q & 7;
        int mt = frag >> 2, kt = frag & 3;
        int m = mt*16 + (lanep & 15);
        int f = m >> 2, gg = m & 3;
        int k = kt*32 + (lanep >> 4)*8 + j;
        float v = 0.f;
        if (isW){
            const float* Ws = (l==0)?Wih_f:(l==1)?Wih_b:Wih_p;
            const float* bb = (l==0)?b_f:(l==1)?b_b:b_p;
            if (k < 100)       v = Ws[(gg*100+f)*100 + k];
            else if (k == 100) v = bb[gg*100+f];          // bias column (x col 100 == 1.0)
        } else {
            const float* Ws = (l==0)?Whh_f:(l==1)?Whh_b:Whh_p;
            if (k < 100)       v = Ws[(gg*100+f)*100 + k];
        }
        (isW ? Wsw3 : Asw3)[e] = f2bu(v);
    } else if (bx < 1375){
        int lane = TID & 63, w = TID >> 6;
        int r = (bx - 1200)*4 + w;            // 0..699
        if (r < 600){
            float x=0.f, y=0.f;
            for (int k=lane;k<600;k+=64){ float wv=W1[r*600+k]; x+=wv*a1[k]; y+=wv*a1[600+k]; }
#pragma unroll
            for (int off=32;off>0;off>>=1){ x+=__shfl_down(x,off,64); y+=__shfl_down(y,off,64); }
            if (lane==0){ w1a[r]=x; w1b[r]=y; }
        } else if (r < 700){
            int f = r-600;
            float x=0.f, y=0.f;
            for (int k=lane;k<100;k+=64){ float wv=W2[f*100+k]; x+=wv*a2[k]; y+=wv*a2[100+k]; }
#pragma unroll
            for (int off=32;off>0;off>>=1){ x+=__shfl_down(x,off,64); y+=__shfl_down(y,off,64); }
            if (lane==0){ w2a[f]=x; w2b[f]=y; }
        }
    } else {
        int e = (bx-1375)*256 + TID;
        if (e < 1454100)            entB[e] = f2bu(ent[e]);
        else if (e < 1477800)       relB[e-1454100] = f2bu(rel[e-1454100]);
        else if (e < 2931900)       ent1B[e-1477800] = f2bu(ent1[e-1477800]);
        else if (e < 2955600)       rel1B[e-2931900] = f2bu(rel1[e-2931900]);
    }
}

// ============ K2: 3xLSTM, fused input-proj + recurrence MFMA, slot-major h -> out6 ============
// One block per 40-sample group; ping-pong HA buffers; x staged per step (L2-hit gathers).
__global__ __launch_bounds__(256, 3) void k_lstm(
    const int* __restrict__ bh, const int* __restrict__ br, const int* __restrict__ bt,
    const unsigned short* __restrict__ entB, const unsigned short* __restrict__ relB,
    const unsigned short* __restrict__ ent1B, const unsigned short* __restrict__ rel1B,
    const unsigned short* __restrict__ Asw3, const unsigned short* __restrict__ Wsw3,
    const float* __restrict__ w2a, const float* __restrict__ w2b,
    unsigned short* __restrict__ out6, float* __restrict__ z2,
    float* __restrict__ out0, float* __restrict__ op0)
{
    __shared__ __align__(16) ushort_t XA[48][136];      // x_t B-frags (col 100 == 1.0 for bias)
    __shared__ __align__(16) ushort_t HA2[2][48][136];  // ping-pong h
    __shared__ float S0o[600];
    __shared__ float S0p[100];
    __shared__ float sc2[40], tc2[40], att2[40];
    __shared__ int sidx[3][40];

    int g = blockIdx.x, m0 = g*40;
    if (TID < 40){
        sidx[0][TID] = bh[m0+TID];
        sidx[1][TID] = br[m0+TID];
        sidx[2][TID] = bt[m0+TID];
    }
    {   // zero XA (6528 shorts) + HA2 (13056 shorts)
        us4 zz; zz[0]=0; zz[1]=0; zz[2]=0; zz[3]=0;
        for (int i=TID; i<1632; i+=256) ((us4*)XA)[i] = zz;
        for (int i=TID; i<3264; i+=256) ((us4*)HA2)[i] = zz;
    }
    __syncthreads();
    if (TID < 48) XA[TID][100] = 0x3F80;   // bf16 1.0 bias column
    __syncthreads();

    int lane = TID & 63;
    int wid  = TID >> 6;
    int l15  = lane & 15;
    int quad = lane >> 4;
    int nmt  = (wid==0) ? 7 : 6;          // m-tiles: wid + 4*i < 25
    bool doS0 = ((g & 1) == 0);
    int rrow = g >> 1;

    float c[21];
    us4 xreg[4];

    // prologue: x rows for step 0 (l=0,t=0 -> head -> entB)
#pragma unroll
    for (int j=0;j<4;j++){
        int idx = TID + j*256;
        if (idx < 1000){
            int s = idx/25, ch = idx - s*25;
            xreg[j] = *(const us4*)(entB + (size_t)sidx[0][s]*100 + ch*4);
        }
    }

    int prevc = -1;
    for (int k=0; k<9; k++){
        int l = k/3, t = k - l*3;
        const ushort_t* Aswl = Asw3 + l*51200;
        const ushort_t* Wswl = Wsw3 + l*51200;
        ushort_t (*hr)[136] = HA2[k & 1];
        ushort_t (*hw)[136] = HA2[(k+1) & 1];

        // ---- S1: write x_t -> XA; store prev h -> out6 (coalesced); prefetch next x
#pragma unroll
        for (int j=0;j<4;j++){
            int idx = TID + j*256;
            if (idx < 1000){
                int s = idx/25, ch = idx - s*25;
                *(us4*)&XA[s][ch*4] = xreg[j];
            }
        }
        if (prevc >= 0){
            unsigned short* base = out6 + (size_t)prevc*8192000 + (size_t)m0*100;
#pragma unroll
            for (int j=0;j<4;j++){
                int idx = TID + j*256;
                if (idx < 1000){
                    int s = idx/25, ch = idx - s*25;
                    *(us4*)(base + s*100 + ch*4) = *(const us4*)&hr[s][ch*4];
                }
            }
        }
        if (k < 8){
            int ln = (k+1)/3, tn = (k+1) - ln*3;
            int pn = (ln==1) ? (2-tn) : tn;
            const ushort_t* tb = (ln==2) ? ((pn==1)? rel1B : ent1B)
                                         : ((pn==1)? relB  : entB);
#pragma unroll
            for (int j=0;j<4;j++){
                int idx = TID + j*256;
                if (idx < 1000){
                    int s = idx/25, ch = idx - s*25;
                    xreg[j] = *(const us4*)(tb + (size_t)sidx[pn][s]*100 + ch*4);
                }
            }
        }
        __syncthreads();

        // ---- S3: per m-tile: A-frags from global (L2), B-frags from LDS, MFMA x2, cell math
        int wbase = (l==0) ? t*200 : (l==1) ? (2-t)*200 + 100 : 0;
#pragma unroll
        for (int i=0;i<7;i++){
            if (i < nmt){
                int mt = wid + 4*i;
                bf16x8 ax[4], ah[4];
#pragma unroll
                for (int kt=0;kt<4;kt++)
                    ax[kt] = *(const bf16x8*)(Wswl + ((mt*4+kt)*64 + lane)*8);
                if (t > 0){
#pragma unroll
                    for (int kt=0;kt<4;kt++)
                        ah[kt] = *(const bf16x8*)(Aswl + ((mt*4+kt)*64 + lane)*8);
                }
                int f = mt*4 + quad;      // 0..99
#pragma unroll
                for (int nt=0;nt<3;nt++){
                    f32x4 acc = (f32x4){0.f,0.f,0.f,0.f};
#pragma unroll
                    for (int kt=0;kt<4;kt++){
                        bf16x8 xf = *(const bf16x8*)&XA[nt*16 + l15][kt*32 + quad*8];
                        acc = __builtin_amdgcn_mfma_f32_16x16x32_bf16(ax[kt], xf, acc, 0, 0, 0);
                    }
                    if (t > 0){
#pragma unroll
                        for (int kt=0;kt<4;kt++){
                            bf16x8 hf = *(const bf16x8*)&hr[nt*16 + l15][kt*32 + quad*8];
                            acc = __builtin_amdgcn_mfma_f32_16x16x32_bf16(ah[kt], hf, acc, 0, 0, 0);
                        }
                    }
                    int s = nt*16 + l15;
                    bool valid = (nt < 2) || (l15 < 8);
                    float cp = (t==0) ? 0.f : c[i*3+nt];
                    float cn = sigm(acc[1])*cp + sigm(acc[0])*tanhx(acc[2]);
                    float h  = sigm(acc[3])*tanhx(cn);
                    c[i*3+nt] = cn;
                    if (valid){
                        hw[s][f] = f2bu(h);
                        if (doS0 && s==0){
                            if (l < 2)        S0o[wbase + f] = h;
                            else if (t == 2)  S0p[f] = h;
                        }
                    }
                }
            }
        }
        prevc = (l < 2) ? (l*3 + t) : -1;
        __syncthreads();
    }
    // final proc-LSTM h is in HA2[1] (step 8 wrote (8+1)&1 = 1)
    ushort_t (*hf)[136] = HA2[1];

    // ---- proc-branch attention (set 2)
    for (int n = wid; n < 40; n += 4){
        float a2=0.f, b2=0.f;
        for (int k=lane;k<100;k+=64){ float v=bfu2f(hf[n][k]); a2 += v*w2a[k]; b2 += v*w2b[k]; }
#pragma unroll
        for (int off=32; off>0; off>>=1){ a2 += __shfl_down(a2,off,64); b2 += __shfl_down(b2,off,64); }
        if (lane==0){ sc2[n]=a2; tc2[n]=b2; }
    }
    __syncthreads();
    if (wid == 0){
        float e = -1e30f;
        if (lane < 40){
            float x = sc2[lane] + tc2[0];
            e = (x > 0.f) ? x : 0.2f*x;
        }
        float mx = e;
#pragma unroll
        for (int off=32;off>0;off>>=1) mx = fmaxf(mx, __shfl_down(mx,off,64));
        mx = __shfl(mx, 0, 64);
        float pexp = (lane<40) ? __expf(e-mx) : 0.f;
        float sm = pexp;
#pragma unroll
        for (int off=32;off>0;off>>=1) sm += __shfl_down(sm,off,64);
        sm = __shfl(sm, 0, 64);
        if (lane < 40){
            float a = pexp/sm - 0.001f;
            att2[lane] = (a > 0.f) ? a : 0.f;
        }
    }
    __syncthreads();
    for (int j=TID; j<100; j+=256){
        float acc = 0.f;
#pragma unroll
        for (int n=0;n<40;n++) acc += att2[n]*bfu2f(hf[n][j]);
        z2[(size_t)g*100 + j] = acc;
    }
    if (doS0){
        for (int j=TID; j<600; j+=256) out0[(size_t)rrow*600 + j] = S0o[j];
        for (int j=TID; j<100; j+=256) op0[(size_t)rrow*100 + j] = S0p[j];
    }
}

// ============ K3: BiLSTM-branch attention from slot-major out6 ============
__global__ __launch_bounds__(256, 3) void k_att(const unsigned short* __restrict__ out6,
    const float* __restrict__ w1a, const float* __restrict__ w1b, float* __restrict__ z)
{
    __shared__ __align__(16) ushort_t RL[40][600];
    __shared__ float sc1[40], tc1[40], att1[40];
    int g = blockIdx.x, m0 = g*40;
#pragma unroll
    for (int cc=0; cc<6; cc++){
        int l = cc/3, t = cc - l*3;
        int sb = (l==0) ? t*200 : (2-t)*200 + 100;
        const unsigned short* base = out6 + (size_t)cc*8192000 + (size_t)m0*100;
        for (int idx=TID; idx<1000; idx+=256){
            int s = idx/25, ch = idx - s*25;
            *(us4*)&RL[s][sb + ch*4] = *(const us4*)(base + s*100 + ch*4);
        }
    }
    __syncthreads();
    int lane = TID & 63, wid = TID >> 6;
    for (int n = wid; n < 40; n += 4){
        float a=0.f, b=0.f;
        for (int k=lane;k<600;k+=64){ float v=bfu2f(RL[n][k]); a += v*w1a[k]; b += v*w1b[k]; }
#pragma unroll
        for (int off=32; off>0; off>>=1){ a += __shfl_down(a,off,64); b += __shfl_down(b,off,64); }
        if (lane==0){ sc1[n]=a; tc1[n]=b; }
    }
    __syncthreads();
    if (wid == 0){
        float e = -1e30f;
        if (lane < 40){
            float x = sc1[lane] + tc1[0];
            e = (x > 0.f) ? x : 0.2f*x;
        }
        float mx = e;
#pragma unroll
        for (int off=32;off>0;off>>=1) mx = fmaxf(mx, __shfl_down(mx,off,64));
        mx = __shfl(mx, 0, 64);
        float pexp = (lane<40) ? __expf(e-mx) : 0.f;
        float sm = pexp;
#pragma unroll
        for (int off=32;off>0;off>>=1) sm += __shfl_down(sm,off,64);
        sm = __shfl(sm, 0, 64);
        if (lane < 40){
            float a = pexp/sm - 0.001f;
            att1[lane] = (a > 0.f) ? a : 0.f;
        }
    }
    __syncthreads();
    for (int j=TID; j<600; j+=256){
        float acc = 0.f;
#pragma unroll
        for (int n=0;n<40;n++) acc += att1[n]*bfu2f(RL[n][j]);
        z[(size_t)g*600 + j] = acc;
    }
}

// ============ K4: merged final GEMMs: y<3 -> oatt (600 col-chunks), y==3 -> oatt2 (100) ====
__global__ __launch_bounds__(256) void k_post(const float* __restrict__ z, const float* __restrict__ z2,
    const float* __restrict__ W1, const float* __restrict__ W2,
    float* __restrict__ oatt, float* __restrict__ oatt2)
{
    extern __shared__ float zl[];
    int y = blockIdx.y;
    const float* zz = (y==3)? z2 : z;
    const float* W  = (y==3)? W2 : W1;
    float* o        = (y==3)? oatt2 : oatt;
    int dim         = (y==3)? 100 : 600;
    int rb = blockIdx.x*16;
    for (int r=0;r<16;r++){
        for (int j=TID;j<dim;j+=256) zl[r*dim+j] = zz[(size_t)(rb+r)*dim + j];
    }
    __syncthreads();
    int cc = (y==3)? TID : y*256 + TID;
    if (cc < dim){
        float acc[16];
#pragma unroll
        for (int r=0;r<16;r++) acc[r]=0.f;
        for (int k=0;k<dim;k++){
            float w = W[(size_t)k*dim + cc];
#pragma unroll
            for (int r=0;r<16;r++) acc[r] += zl[r*dim+k]*w;
        }
        for (int r=0;r<16;r++) o[(size_t)(rb+r)*dim + cc] = acc[r];
    }
}

__global__ void k_sentinel(float* o, float v){ o[0] = v; }

extern "C" void kernel_launch(void* const* d_in, const int* in_sizes, int n_in,
                              void* d_out, int out_size, void* d_ws, size_t ws_size,
                              hipStream_t stream)
{
    const int*   bh   = (const int*)d_in[0];
    const int*   br   = (const int*)d_in[1];
    const int*   bt   = (const int*)d_in[2];
    const float* ent  = (const float*)d_in[3];
    const float* rel  = (const float*)d_in[4];
    const float* ent1 = (const float*)d_in[5];
    const float* rel1 = (const float*)d_in[6];
    const float* Wih_f = (const float*)d_in[7];
    const float* Whh_f = (const float*)d_in[8];
    const float* b_f   = (const float*)d_in[9];
    const float* Wih_b = (const float*)d_in[10];
    const float* Whh_b = (const float*)d_in[11];
    const float* b_b   = (const float*)d_in[12];
    const float* Wih_p = (const float*)d_in[13];
    const float* Whh_p = (const float*)d_in[14];
    const float* b_p   = (const float*)d_in[15];
    const float* W1 = (const float*)d_in[16];
    const float* a1 = (const float*)d_in[17];
    const float* W2 = (const float*)d_in[18];
    const float* a2 = (const float*)d_in[19];

    char* wsb = (char*)d_ws;
    size_t off = 0;
    auto alloc = [&](size_t bytes) -> char* {
        char* p = wsb + off;
        off += (bytes + 255) & ~(size_t)255;
        return p;
    };
    unsigned short* entB  = (unsigned short*)alloc((size_t)1454100*2);
    unsigned short* relB  = (unsigned short*)alloc((size_t)23700*2);
    unsigned short* ent1B = (unsigned short*)alloc((size_t)1454100*2);
    unsigned short* rel1B = (unsigned short*)alloc((size_t)23700*2);
    unsigned short* Asw3  = (unsigned short*)alloc((size_t)153600*2);
    unsigned short* Wsw3  = (unsigned short*)alloc((size_t)153600*2);
    float* w1a = (float*)alloc(600*4);
    float* w1b = (float*)alloc(600*4);
    float* w2a = (float*)alloc(100*4);
    float* w2b = (float*)alloc(100*4);
    float* z   = (float*)alloc((size_t)2048*600*4);
    float* z2  = (float*)alloc((size_t)2048*100*4);
    unsigned short* out6 = (unsigned short*)alloc((size_t)49152000*2);   // 6 x 81920 x 100, slot-major

    float* dout  = (float*)d_out;
    float* out0  = dout;              // out2[:,0,:]  1024*600
    float* oatt  = dout + 614400;     // out_att      2048*600
    float* op0   = dout + 1843200;    // op2[:,0,:]   1024*100
    float* oatt2 = dout + 1945600;    // output_att   2048*100

    if (ws_size < off){
        k_sentinel<<<1,1,0,stream>>>(dout, (float)ws_size);
        return;
    }

    k_prep<<<12923, 256, 0, stream>>>(Wih_f, Wih_b, Wih_p, Whh_f, Whh_b, Whh_p,
                                      b_f, b_b, b_p, W1, a1, W2, a2,
                                      ent, rel, ent1, rel1,
                                      Asw3, Wsw3, w1a, w1b, w2a, w2b,
                                      entB, relB, ent1B, rel1B);

    k_lstm<<<2048, 256, 0, stream>>>(bh, br, bt, entB, relB, ent1B, rel1B,
                                     Asw3, Wsw3, w2a, w2b, out6, z2, out0, op0);

    k_att<<<2048, 256, 0, stream>>>(out6, w1a, w1b, z);

    k_post<<<dim3(128,4), 256, 16*600*4, stream>>>(z, z2, W1, W2, oatt, oatt2);
}